// Round 11
// baseline (1993.956 us; speedup 1.0000x reference)
//
#include <hip/hip_runtime.h>

// DynamicRNNEncoder on MI355X — round 11.
// Wave-autonomous redesign of R9: each wave owns (16 batches x 4 units) end to
// end — MFMA, per-wave LDS transpose (lgkm-only, no block barrier), parallel
// epilogue (lane = batch x unit), private sc stores + drain, per-wave arrive.
// hrdy: 64 lines x 8 main-wave arrivals; dner: 32 lines x 8 dyn-wave arrivals.
// Per-lane resolve; merged rc fixup (hd panel + cd) under one dner poll.

typedef _Float16 f16;
typedef _Float16 f16x8 __attribute__((ext_vector_type(8)));
typedef float f32x4 __attribute__((ext_vector_type(4)));

#define B_ 64
#define T_ 256
#define H_ 512
#define EN_ 256
#define ET_ 256
#define D_ 256
#define VN_ 300
#define VS_ 100

#define NB_MAIN_ 128   // 4 main h-dims each
#define NB_DYN_ 64     // 4 dyn dims each
#define NBLK_ 192
#define NTHR_ 256
#define POLL_CAP_ (1u << 22)
#define DNER_W_ 1024   // dner region start (word index); hrdy = words 0..1023

// ---- workspace layout (bytes) ----
static constexpr size_t OFF_CNT  = 0;                                   // 8KB counters
static constexpr size_t OFF_EMBN = 8192;                                // embN f16  [300][256]
static constexpr size_t OFF_EMBT = OFF_EMBN + (size_t)VN_ * EN_ * 2;    // embT f16  [100][256]
static constexpr size_t OFF_DINH = OFF_EMBT + (size_t)VS_ * ET_ * 2;    // dyn_init_h f16 [256]
static constexpr size_t OFF_PREV = OFF_DINH + 1024;                     // prev int32 [T][B]
static constexpr size_t OFF_HH   = OFF_PREV + (size_t)T_ * B_ * 4;      // Hhist f16 tiled [T+1][64][64][8]
static constexpr size_t OFF_HD   = OFF_HH + (size_t)(T_ + 1) * B_ * H_ * 2; // HdHist f16 [T][B][D]
static constexpr size_t OFF_CD   = OFF_HD + (size_t)T_ * B_ * D_ * 2;   // CdHist f32 [T][B][D]
static constexpr size_t WS_NEED  = OFF_CD + (size_t)T_ * B_ * D_ * 4;   // ~42.3 MB

struct RnnParams {
  const int* n_input; const int* t_input; const int* s2d;
  const float* W_ih; const float* W_hh; const float* b_ih; const float* b_hh;
  const float* Wd_ih; const float* Wd_hh; const float* bd_ih; const float* bd_hh;
  const float* cell_init; const float* dyn_init_c;
  const f16* embN16; const f16* embT16; const f16* dynih16;
  const int* prev;
  f16* Hhist; f16* HdHist; float* CdHist;
  float* out; unsigned* cnt;
};

__device__ __forceinline__ float sigm(float x) { return 1.f / (1.f + __expf(-x)); }
__device__ __forceinline__ float tanh_fast(float x) {
  float e = __expf(2.f * x);
  return 1.f - 2.f / (e + 1.f);
}
__device__ __forceinline__ unsigned cld(const unsigned* w) {
  return __hip_atomic_load(w, __ATOMIC_RELAXED, __HIP_MEMORY_SCOPE_AGENT);
}

// ---- setup: f16 conversions, tiled Hhist[0] init, counter reset ----
__global__ void setup_kernel(const float* embN, const float* embT,
                             const float* hid_init, const float* dyn_init_h,
                             f16* embN16, f16* embT16, f16* dynih16,
                             f16* Hhist0, unsigned* cnt) {
  int i = blockIdx.x * blockDim.x + threadIdx.x;
  if (i < 2048)      cnt[i] = 0u;
  if (i < VN_ * EN_) embN16[i] = (f16)embN[i];
  if (i < VS_ * ET_) embT16[i] = (f16)embT[i];
  if (i < D_)        dynih16[i] = (f16)dyn_init_h[i];
  if (i < B_ * H_) {                      // tiled: (b,k) -> (k>>3)*512 + b*8 + (k&7)
    int b = i >> 9, k = i & 511;
    Hhist0[(k >> 3) * 512 + b * 8 + (k & 7)] = (f16)hid_init[k];
  }
  __threadfence();
}

// ---- prev-occurrence table ----
__global__ void prev_kernel(const int* t_input, const int* s2d, int* prev) {
  int idx = blockIdx.x * blockDim.x + threadIdx.x;
  if (idx < B_ * T_) {
    int b = idx / T_, t = idx % T_;
    int tt = t_input[b * T_ + t];
    int p = -1;
    if (s2d[tt] != tt) {
      for (int q = t - 1; q >= 0; --q)
        if (t_input[b * T_ + q] == tt) { p = q; break; }
    }
    prev[t * B_ + b] = p;
  }
  __threadfence();
}

// per-lane resolve for step s, batch bg; epilogue dim = u0+eui.
// rc = row whose hd/cd source (pv >= s-2) is untrusted at prefetch time.
__device__ __forceinline__ void resolve_lane(const RnnParams& p, bool isDyn, int s,
                                             int bg, int eui, int u0,
                                             const f16*& pN, const f16*& pX,
                                             const float*& pC, int& dynw, int& rc) {
  const int nt = p.n_input[bg * T_ + s];
  pN = p.embN16 + (size_t)nt * EN_;
  const int tt = p.t_input[bg * T_ + s];
  const int pv = p.prev[s * B_ + bg];
  rc = (pv >= 0 && pv + 2 >= s) ? 1 : 0;
  const f16* hd = (pv >= 0) ? (p.HdHist + ((size_t)pv * B_ + bg) * D_) : p.dynih16;
  const int s2 = p.s2d[tt];
  const bool st = (s2 == tt);
  if (!isDyn) {
    pX = st ? (p.embT16 + (size_t)s2 * ET_) : hd;
    if (st) rc = 0;                       // static rows never need reload
    dynw = 0;
  } else {
    pX = hd;
    pC = ((pv >= 0) ? (p.CdHist + ((size_t)pv * B_ + bg) * D_) : p.dyn_init_c)
         + u0 + eui;
    dynw = st ? 0 : 1;
  }
}

// ---- main persistent recurrent kernel ----
__global__ __launch_bounds__(NTHR_, 1) void rnn_main(RnnParams p) {
  const int blk  = blockIdx.x;
  const int tid  = threadIdx.x;
  const int wave = tid >> 6;
  const int lane = tid & 63;
  const bool isDyn = (blk >= NB_MAIN_);
  const int u0 = isDyn ? (blk - NB_MAIN_) * 4 : blk * 4;

  __threadfence();   // one-time: invalidate caches to the coherent point

  __shared__ float s_scr[2][4][16][17];   // [parity][wave][m][n]

  // ---- one-time: weights into registers ----
  // lane l supplies B-frag elems: B[k = s*32 + (l>>4)*8 + j][n = l&15]
  const int nIdx = lane & 15;
  const int wui = nIdx & 3, wgate = nIdx >> 2;
  const int ko = (lane >> 4) * 8;
  f16x8 w[32];
  if (!isDyn) {
    const int r = wgate * H_ + u0 + wui;
#pragma unroll
    for (int s = 0; s < 32; ++s) {
      const int k = s * 32 + ko;           // [0,256)=embN [256,512)=h_tensor [512,1024)=h
      const float* src = (k < 512) ? (p.W_ih + (size_t)r * 512 + k)
                                   : (p.W_hh + (size_t)r * 512 + (k - 512));
      f16x8 v;
#pragma unroll
      for (int j = 0; j < 8; ++j) v[j] = (f16)src[j];
      w[s] = v;
    }
  } else {
    const int r = wgate * D_ + u0 + wui;
#pragma unroll
    for (int s = 0; s < 32; ++s) {
      const int k = s * 32 + ko;           // [0,256)=embN [256,768)=h [768,1024)=hd_prev
      const float* src = (k < 768) ? (p.Wd_ih + (size_t)r * 768 + k)
                                   : (p.Wd_hh + (size_t)r * 256 + (k - 768));
      f16x8 v;
#pragma unroll
      for (int j = 0; j < 8; ++j) v[j] = (f16)src[j];
      w[s] = v;
    }
  }

  // ---- per-lane geometry ----
  const int bq  = lane & 15;               // batch within wave group
  const int eui = lane >> 4;               // epilogue unit within block
  const int bg  = (wave << 4) + bq;        // global batch
  const int hoff = (eui << 9) + (bq << 3) + (wave << 7);  // tiled-h base (f16)
  const unsigned arriveW = isDyn
      ? (unsigned)(DNER_W_ + ((((blk - NB_MAIN_) << 2) | wave) & 31) * 16)
      : (unsigned)(((((blk << 2) | wave)) & 63) * 16);

  float bias_g[4];
#pragma unroll
  for (int g = 0; g < 4; ++g)
    bias_g[g] = isDyn ? (p.bd_ih[g * D_ + u0 + eui] + p.bd_hh[g * D_ + u0 + eui])
                      : (p.b_ih[g * H_ + u0 + eui] + p.b_hh[g * H_ + u0 + eui]);
  float creg = isDyn ? 0.f : p.cell_init[u0 + eui];

  // ---- resolve + prefetch step 0 ----
  const f16 *pN, *pX; const float* pC = p.dyn_init_c; int dynw = 0, rc = 0;
  resolve_lane(p, isDyn, 0, bg, eui, u0, pN, pX, pC, dynw, rc);
  f16x8 pf[16];
#pragma unroll
  for (int i = 0; i < 8; ++i) pf[i] = *(const f16x8*)(pN + i * 32 + ko);
#pragma unroll
  for (int i = 0; i < 8; ++i) pf[8 + i] = *(const f16x8*)(pX + i * 32 + ko);
  float cvp = isDyn ? *pC : 0.f;

  for (int t = 0; t < T_; ++t) {
    const int pb = t & 1;

    // ---- release: each lane polls one of 64 hrdy lines ----
    if (t) {
      const unsigned* wp = p.cnt + (lane << 4);
      const unsigned tgt = 8u * (unsigned)t;
      unsigned it = 0;
      while (__any(cld(wp) < tgt) && ++it < POLL_CAP_)
        __builtin_amdgcn_s_sleep(1);
      __builtin_amdgcn_sched_barrier(0);
    }

    // ---- load h[t] from tiled layout ----
    const f16* pH2 = p.Hhist + (size_t)t * 32768 + hoff;
    f16x8 hh[16];
#pragma unroll
    for (int i = 0; i < 16; ++i) hh[i] = *(const f16x8*)(pH2 + i * 2048);

    // ---- rare fixup: rows with pv >= t-2 (one dner poll, batched sc reload) ----
    if (__any(rc)) {
      const unsigned* wp = p.cnt + DNER_W_ + ((lane & 31) << 4);
      const unsigned tgt = 8u * (unsigned)t;
      unsigned it = 0;
      while (__any(cld(wp) < tgt) && ++it < POLL_CAP_)
        __builtin_amdgcn_s_sleep(1);
      if (rc) {
#pragma unroll
        for (int i = 0; i < 8; ++i)
          asm volatile("global_load_dwordx4 %0, %1, off sc0 sc1"
                       : "=&v"(pf[8 + i]) : "v"(pX + i * 32 + ko));
        if (isDyn)
          asm volatile("global_load_dword %0, %1, off sc0 sc1"
                       : "=&v"(cvp) : "v"(pC));
      }
      asm volatile("s_waitcnt vmcnt(0)" ::: "memory");
      __builtin_amdgcn_sched_barrier(0);
    }

    // ---- 32 MFMAs ----
    f32x4 ac[4] = {{0,0,0,0},{0,0,0,0},{0,0,0,0},{0,0,0,0}};
    if (!isDyn) {
#pragma unroll
      for (int i = 0; i < 8; ++i)
        ac[i & 3] = __builtin_amdgcn_mfma_f32_16x16x32_f16(pf[i], w[i], ac[i & 3], 0, 0, 0);
#pragma unroll
      for (int i = 0; i < 8; ++i)
        ac[i & 3] = __builtin_amdgcn_mfma_f32_16x16x32_f16(pf[8 + i], w[8 + i], ac[i & 3], 0, 0, 0);
#pragma unroll
      for (int i = 0; i < 16; ++i)
        ac[i & 3] = __builtin_amdgcn_mfma_f32_16x16x32_f16(hh[i], w[16 + i], ac[i & 3], 0, 0, 0);
    } else {
#pragma unroll
      for (int i = 0; i < 8; ++i)
        ac[i & 3] = __builtin_amdgcn_mfma_f32_16x16x32_f16(pf[i], w[i], ac[i & 3], 0, 0, 0);
#pragma unroll
      for (int i = 0; i < 8; ++i)
        ac[i & 3] = __builtin_amdgcn_mfma_f32_16x16x32_f16(pf[8 + i], w[24 + i], ac[i & 3], 0, 0, 0);
#pragma unroll
      for (int i = 0; i < 16; ++i)
        ac[i & 3] = __builtin_amdgcn_mfma_f32_16x16x32_f16(hh[i], w[8 + i], ac[i & 3], 0, 0, 0);
    }
    f32x4 acc = (ac[0] + ac[1]) + (ac[2] + ac[3]);

    // ---- per-wave transpose (NO block barrier; wave-lockstep + lgkm) ----
    // D[m][n]: m = (lane>>4)*4 + j (= eui*4+j), n = lane&15 (= bq)
#pragma unroll
    for (int j = 0; j < 4; ++j)
      s_scr[pb][wave][(eui << 2) + j][bq] = acc[j];
    asm volatile("s_waitcnt lgkmcnt(0)" ::: "memory");
    __builtin_amdgcn_sched_barrier(0);
    const float g0 = s_scr[pb][wave][bq][eui]      + bias_g[0];
    const float g1 = s_scr[pb][wave][bq][4 + eui]  + bias_g[1];
    const float g2 = s_scr[pb][wave][bq][8 + eui]  + bias_g[2];
    const float g3 = s_scr[pb][wave][bq][12 + eui] + bias_g[3];

    // ---- parallel epilogue: this lane owns (batch bg, dim u0+eui) ----
    if (!isDyn) {
      const float c = sigm(g1) * creg + sigm(g0) * tanh_fast(g2);
      creg = c;
      const float h = sigm(g3) * tanh_fast(c);
      p.out[((size_t)bg * T_ + t) * H_ + u0 + eui] = h;
      const int u = u0 + eui;
      f16* hp = p.Hhist + (size_t)(t + 1) * 32768 + ((u >> 3) << 9) + (bg << 3) + (u & 7);
      union { f16 hf; unsigned short us; } pk; pk.hf = (f16)h;
      asm volatile("global_store_short %0, %1, off sc0 sc1"
                   :: "v"(hp), "v"((unsigned)pk.us) : "memory");
    } else {
      const float c = sigm(g1) * cvp + sigm(g0) * tanh_fast(g2);
      const float h = sigm(g3) * tanh_fast(c);
      if (dynw) {
        f16* hp = p.HdHist + ((size_t)t * B_ + bg) * D_ + u0 + eui;
        float* cp = p.CdHist + ((size_t)t * B_ + bg) * D_ + u0 + eui;
        union { f16 hf; unsigned short us; } pk; pk.hf = (f16)h;
        asm volatile("global_store_short %0, %1, off sc0 sc1"
                     :: "v"(hp), "v"((unsigned)pk.us) : "memory");
        asm volatile("global_store_dword %0, %1, off sc0 sc1"
                     :: "v"(cp), "v"(c) : "memory");
      }
    }

    if (t + 1 < T_) {
      // ---- private drain + per-wave arrive ----
      asm volatile("s_waitcnt vmcnt(0)" ::: "memory");
      if (lane == 0)
        __hip_atomic_fetch_add(&p.cnt[arriveW], 1u, __ATOMIC_RELAXED,
                               __HIP_MEMORY_SCOPE_AGENT);

      // ---- resolve t+1 (per lane), lagged dner gate, prefetch ----
      resolve_lane(p, isDyn, t + 1, bg, eui, u0, pN, pX, pC, dynw, rc);
      if (t >= 2) {
        const unsigned* wp = p.cnt + DNER_W_ + ((lane & 31) << 4);
        const unsigned tgt = 8u * (unsigned)(t - 1);   // dyn step t-2 done
        unsigned it = 0;
        while (__any(cld(wp) < tgt) && ++it < POLL_CAP_)
          __builtin_amdgcn_s_sleep(1);
      }
      __builtin_amdgcn_sched_barrier(0);
#pragma unroll
      for (int i = 0; i < 8; ++i) pf[i] = *(const f16x8*)(pN + i * 32 + ko);
#pragma unroll
      for (int i = 0; i < 8; ++i) pf[8 + i] = *(const f16x8*)(pX + i * 32 + ko);
      if (isDyn) cvp = *pC;
    }
  }
}

extern "C" void kernel_launch(void* const* d_in, const int* in_sizes, int n_in,
                              void* d_out, int out_size, void* d_ws, size_t ws_size,
                              hipStream_t stream) {
  (void)in_sizes; (void)n_in; (void)out_size;
  const int* n_input   = (const int*)d_in[0];
  const int* t_input   = (const int*)d_in[1];
  const int* s2d       = (const int*)d_in[3];
  const float* embN    = (const float*)d_in[5];
  const float* embT    = (const float*)d_in[6];
  const float* W_ih    = (const float*)d_in[7];
  const float* W_hh    = (const float*)d_in[8];
  const float* b_ih    = (const float*)d_in[9];
  const float* b_hh    = (const float*)d_in[10];
  const float* Wd_ih   = (const float*)d_in[11];
  const float* Wd_hh   = (const float*)d_in[12];
  const float* bd_ih   = (const float*)d_in[13];
  const float* bd_hh   = (const float*)d_in[14];
  const float* hid_init  = (const float*)d_in[15];
  const float* cell_init = (const float*)d_in[16];
  const float* dyn_init_h = (const float*)d_in[17];
  const float* dyn_init_c = (const float*)d_in[18];

  char* ws = (char*)d_ws;
  unsigned* cnt  = (unsigned*)(ws + OFF_CNT);
  f16* embN16    = (f16*)(ws + OFF_EMBN);
  f16* embT16    = (f16*)(ws + OFF_EMBT);
  f16* dynih16   = (f16*)(ws + OFF_DINH);
  int* prev      = (int*)(ws + OFF_PREV);
  f16* Hhist     = (f16*)(ws + OFF_HH);
  f16* HdHist    = (f16*)(ws + OFF_HD);
  float* CdHist  = (float*)(ws + OFF_CD);
  if (ws_size < WS_NEED) return;

  setup_kernel<<<dim3((VN_ * EN_ + NTHR_ - 1) / NTHR_), dim3(NTHR_), 0, stream>>>(
      embN, embT, hid_init, dyn_init_h, embN16, embT16, dynih16, Hhist, cnt);
  prev_kernel<<<dim3((B_ * T_ + NTHR_ - 1) / NTHR_), dim3(NTHR_), 0, stream>>>(
      t_input, s2d, prev);

  RnnParams prm;
  prm.n_input = n_input; prm.t_input = t_input; prm.s2d = s2d;
  prm.W_ih = W_ih; prm.W_hh = W_hh; prm.b_ih = b_ih; prm.b_hh = b_hh;
  prm.Wd_ih = Wd_ih; prm.Wd_hh = Wd_hh; prm.bd_ih = bd_ih; prm.bd_hh = bd_hh;
  prm.cell_init = cell_init; prm.dyn_init_c = dyn_init_c;
  prm.embN16 = embN16; prm.embT16 = embT16; prm.dynih16 = dynih16;
  prm.prev = prev; prm.Hhist = Hhist; prm.HdHist = HdHist; prm.CdHist = CdHist;
  prm.out = (float*)d_out; prm.cnt = cnt;

  void* args[] = { &prm };
  hipError_t e = hipLaunchCooperativeKernel((const void*)rnn_main,
                                            dim3(NBLK_), dim3(NTHR_), args, 0, stream);
  if (e != hipSuccess) {
    rnn_main<<<dim3(NBLK_), dim3(NTHR_), 0, stream>>>(prm);
  }
}

// Round 12
// 1161.884 us; speedup vs baseline: 1.7161x; 1.7161x over previous
//
#include <hip/hip_runtime.h>

// DynamicRNNEncoder on MI355X — round 12.
// R9 anchor (1217us) + two surgical deltas:
//  (1) Hhist tile [t][u>>2][b][4]: publish = fully-covered contiguous 512B
//      per block (no partial-line write-through merge at the IF); consumer
//      reads 32x8B (same bytes, contiguous 512B runs per wave).
//  (2) out store moved after the arrive (off the drain critical path).

typedef _Float16 f16;
typedef _Float16 f16x4 __attribute__((ext_vector_type(4)));
typedef _Float16 f16x8 __attribute__((ext_vector_type(8)));
typedef float f32x4 __attribute__((ext_vector_type(4)));

#define B_ 64
#define T_ 256
#define H_ 512
#define EN_ 256
#define ET_ 256
#define D_ 256
#define VN_ 300
#define VS_ 100

#define NB_MAIN_ 128   // 4 main units (16 gate rows) each
#define NB_DYN_ 64     // 4 dyn units each
#define NBLK_ 192
#define NTHR_ 256
#define NSH_ 64        // barrier counter shards (64B apart)
#define PER_SHARD_ (NBLK_ / NSH_)   // 3
#define POLL_CAP_ (1u << 22)

// ---- workspace layout (bytes) ----
static constexpr size_t OFF_CNT  = 0;                                   // 4KB counters
static constexpr size_t OFF_EMBN = 4096;                                // embN f16  [300][256]
static constexpr size_t OFF_EMBT = OFF_EMBN + (size_t)VN_ * EN_ * 2;    // embT f16  [100][256]
static constexpr size_t OFF_DINH = OFF_EMBT + (size_t)VS_ * ET_ * 2;    // dyn_init_h f16 [256]
static constexpr size_t OFF_PREV = OFF_DINH + 1024;                     // prev int32 [T][B]
static constexpr size_t OFF_HH   = OFF_PREV + (size_t)T_ * B_ * 4;      // Hhist f16 tiled [T+1][128][64][4]
static constexpr size_t OFF_HD   = OFF_HH + (size_t)(T_ + 1) * B_ * H_ * 2; // HdHist f16 [T][B][D]
static constexpr size_t OFF_CD   = OFF_HD + (size_t)T_ * B_ * D_ * 2;   // CdHist f32 [T][B][D]
static constexpr size_t WS_NEED  = OFF_CD + (size_t)T_ * B_ * D_ * 4;   // ~42.3 MB

struct RnnParams {
  const int* n_input; const int* t_input; const int* s2d;
  const float* W_ih; const float* W_hh; const float* b_ih; const float* b_hh;
  const float* Wd_ih; const float* Wd_hh; const float* bd_ih; const float* bd_hh;
  const float* cell_init; const float* dyn_init_c;
  const f16* embN16; const f16* embT16; const f16* dynih16;
  const int* prev;
  f16* Hhist; f16* HdHist; float* CdHist;
  float* out; unsigned* cnt;
};

__device__ __forceinline__ float sigm(float x) { return 1.f / (1.f + __expf(-x)); }
__device__ __forceinline__ float tanh_fast(float x) {
  float e = __expf(2.f * x);
  return 1.f - 2.f / (e + 1.f);
}

// ---- coherent-point helpers ----
__device__ __forceinline__ void cstore8(void* p, unsigned long long v) {
  __hip_atomic_store((unsigned long long*)p, v, __ATOMIC_RELAXED,
                     __HIP_MEMORY_SCOPE_AGENT);
}
__device__ __forceinline__ void cstore16(void* p, f32x4 v) {
  asm volatile("global_store_dwordx4 %0, %1, off sc0 sc1"
               :: "v"(p), "v"(v) : "memory");
}
__device__ __forceinline__ float4 scload16f(const float* p) {
  float4 v;
  asm volatile("global_load_dwordx4 %0, %1, off sc0 sc1\n\ts_waitcnt vmcnt(0)"
               : "=&v"(v) : "v"(p) : "memory");
  return v;
}
// lgkm-only block barrier (no vmcnt drain on the critical path)
__device__ __forceinline__ void lds_barrier() {
  asm volatile("s_waitcnt lgkmcnt(0)\n\ts_barrier" ::: "memory");
}

// ---- setup: f16 conversions, tiled Hhist[0] init, counter reset ----
__global__ void setup_kernel(const float* embN, const float* embT,
                             const float* hid_init, const float* dyn_init_h,
                             f16* embN16, f16* embT16, f16* dynih16,
                             f16* Hhist0, unsigned* cnt) {
  int i = blockIdx.x * blockDim.x + threadIdx.x;
  if (i < 1024)      cnt[i] = 0u;
  if (i < VN_ * EN_) embN16[i] = (f16)embN[i];
  if (i < VS_ * ET_) embT16[i] = (f16)embT[i];
  if (i < D_)        dynih16[i] = (f16)dyn_init_h[i];
  if (i < B_ * H_) {                      // tiled: (b,k) -> (k>>2)*256 + b*4 + (k&3)
    int b = i >> 9, k = i & 511;
    Hhist0[(k >> 2) * 256 + b * 4 + (k & 3)] = (f16)hid_init[k];
  }
  __threadfence();
}

// ---- prev-occurrence table ----
__global__ void prev_kernel(const int* t_input, const int* s2d, int* prev) {
  int idx = blockIdx.x * blockDim.x + threadIdx.x;
  if (idx < B_ * T_) {
    int b = idx / T_, t = idx % T_;
    int tt = t_input[b * T_ + t];
    int p = -1;
    if (s2d[tt] != tt) {
      for (int q = t - 1; q >= 0; --q)
        if (t_input[b * T_ + q] == tt) { p = q; break; }
    }
    prev[t * B_ + b] = p;
  }
  __threadfence();
}

// resolve pointers for step t; rc flags rows with pv == tprev (in flight when
// prefetched -> sc-hardened reload after the next release).
__device__ __forceinline__ void resolve(const RnnParams& p, bool isDyn, int t, int b,
                                        int tprev,
                                        const f16** aN, const f16** aX,
                                        const float** aC, int* dynw, int* rc) {
  const int nt = p.n_input[b * T_ + t];
  aN[b] = p.embN16 + (size_t)nt * EN_;
  const int tt = p.t_input[b * T_ + t];
  const int pv = p.prev[t * B_ + b];
  rc[b] = (pv >= 0 && pv == tprev) ? 1 : 0;
  const f16* hd = (pv >= 0) ? (p.HdHist + ((size_t)pv * B_ + b) * D_) : p.dynih16;
  const int s2 = p.s2d[tt];
  const bool st = (s2 == tt);
  if (!isDyn) {
    aX[b] = st ? (p.embT16 + (size_t)s2 * ET_) : hd;
  } else {
    aX[b] = hd;
    aC[b] = (pv >= 0) ? (p.CdHist + ((size_t)pv * B_ + b) * D_) : p.dyn_init_c;
    dynw[b] = st ? 0 : 1;
  }
}

// ---- main persistent recurrent kernel ----
__global__ __launch_bounds__(NTHR_, 1) void rnn_main(RnnParams p) {
  const int blk  = blockIdx.x;
  const int tid  = threadIdx.x;
  const int wave = tid >> 6;
  const int lane = tid & 63;
  const bool isDyn = (blk >= NB_MAIN_);
  const int u0 = isDyn ? (blk - NB_MAIN_) * 4 : blk * 4;

  __threadfence();   // one-time: invalidate caches to the coherent point

  __shared__ float s_bias[16];
  __shared__ float s_scr[64][17];
  __shared__ const f16*  s_aN[2][64];
  __shared__ const f16*  s_aX[2][64];
  __shared__ const float* s_aC[2][64];
  __shared__ int s_dynw[2][64];
  __shared__ int s_rc[2][64];

  // ---- one-time: weights into registers ----
  // lane l supplies B-frag elems: B[k = s*32 + (l>>4)*8 + j][n = l&15]
  const int nIdx = lane & 15;
  const int ui = nIdx & 3, gate = nIdx >> 2;
  const int ko = (lane >> 4) * 8;
  f16x8 w[32];
  if (!isDyn) {
    const int r = gate * H_ + u0 + ui;
#pragma unroll
    for (int s = 0; s < 32; ++s) {
      const int k = s * 32 + ko;           // [0,256)=embN [256,512)=h_tensor [512,1024)=h
      const float* src = (k < 512) ? (p.W_ih + (size_t)r * 512 + k)
                                   : (p.W_hh + (size_t)r * 512 + (k - 512));
      f16x8 v;
#pragma unroll
      for (int j = 0; j < 8; ++j) v[j] = (f16)src[j];
      w[s] = v;
    }
  } else {
    const int r = gate * D_ + u0 + ui;
#pragma unroll
    for (int s = 0; s < 32; ++s) {
      const int k = s * 32 + ko;           // [0,256)=embN [256,768)=h [768,1024)=hd_prev
      const float* src = (k < 768) ? (p.Wd_ih + (size_t)r * 768 + k)
                                   : (p.Wd_hh + (size_t)r * 256 + (k - 768));
      f16x8 v;
#pragma unroll
      for (int j = 0; j < 8; ++j) v[j] = (f16)src[j];
      w[s] = v;
    }
  }
  if (tid < 16) {
    int g2 = tid >> 2, un2 = tid & 3;
    s_bias[tid] = isDyn ? (p.bd_ih[g2 * D_ + u0 + un2] + p.bd_hh[g2 * D_ + u0 + un2])
                        : (p.b_ih[g2 * H_ + u0 + un2] + p.b_hh[g2 * H_ + u0 + un2]);
  }
  float creg[4] = {0.f, 0.f, 0.f, 0.f};
  if (tid < 64 && !isDyn) {
#pragma unroll
    for (int un = 0; un < 4; ++un) creg[un] = p.cell_init[u0 + un];
  }
  if (tid < 64)
    resolve(p, isDyn, 0, tid, -1, s_aN[0], s_aX[0], s_aC[0], s_dynw[0], s_rc[0]);
  __syncthreads();

  // ---- pre-loop prefetch for t=0 ----
  const int b = (wave << 4) + (lane & 15);
  f16x8 pf[16];      // [0..7]=embN slices, [8..15]=h_tensor/hd slices
  float4 cvp = {0.f, 0.f, 0.f, 0.f};
  {
    const f16* pN = s_aN[0][b];
    const f16* pX = s_aX[0][b];
#pragma unroll
    for (int i = 0; i < 8; ++i) pf[i] = *(const f16x8*)(pN + i * 32 + ko);
#pragma unroll
    for (int i = 0; i < 8; ++i) pf[8 + i] = *(const f16x8*)(pX + i * 32 + ko);
    if (isDyn && tid < 64) cvp = *(const float4*)(s_aC[0][tid] + u0);
  }
  // tiled-h per-lane base (f16 units): group (ko>>2) + batch b
  const int hoff = ((ko >> 2) << 8) + (b << 2);

  for (int t = 0; t < T_; ++t) {
    const int pb = t & 1;

    // ---- load h[t] from 4-dim-slot tiled layout: 2x8B per slice ----
    const f16* pH2 = p.Hhist + (size_t)t * 32768 + hoff;
    f16x8 hh[16];
#pragma unroll
    for (int i = 0; i < 16; ++i) {
      f16x4* h4 = (f16x4*)&hh[i];
      h4[0] = *(const f16x4*)(pH2 + i * 2048);
      h4[1] = *(const f16x4*)(pH2 + i * 2048 + 256);
    }

    // ---- rare fixup: hd rows with pv == t-1 (sc-hardened batched reload) ----
    {
      const int need = s_rc[pb][b];
      if (__any(need)) {
        if (need) {
          const f16* pX = s_aX[pb][b];
#pragma unroll
          for (int i = 0; i < 8; ++i)
            asm volatile("global_load_dwordx4 %0, %1, off sc0 sc1"
                         : "=&v"(pf[8 + i]) : "v"(pX + i * 32 + ko));
        }
        asm volatile("s_waitcnt vmcnt(0)" ::: "memory");
        __builtin_amdgcn_sched_barrier(0);
      }
    }

    // ---- 32 MFMAs (x-part first; hh flight hides under them) ----
    f32x4 ac[4] = {{0,0,0,0},{0,0,0,0},{0,0,0,0},{0,0,0,0}};
    if (!isDyn) {
#pragma unroll
      for (int i = 0; i < 8; ++i)
        ac[i & 3] = __builtin_amdgcn_mfma_f32_16x16x32_f16(pf[i], w[i], ac[i & 3], 0, 0, 0);
#pragma unroll
      for (int i = 0; i < 8; ++i)
        ac[i & 3] = __builtin_amdgcn_mfma_f32_16x16x32_f16(pf[8 + i], w[8 + i], ac[i & 3], 0, 0, 0);
#pragma unroll
      for (int i = 0; i < 16; ++i)
        ac[i & 3] = __builtin_amdgcn_mfma_f32_16x16x32_f16(hh[i], w[16 + i], ac[i & 3], 0, 0, 0);
    } else {
#pragma unroll
      for (int i = 0; i < 8; ++i)
        ac[i & 3] = __builtin_amdgcn_mfma_f32_16x16x32_f16(pf[i], w[i], ac[i & 3], 0, 0, 0);
#pragma unroll
      for (int i = 0; i < 8; ++i)
        ac[i & 3] = __builtin_amdgcn_mfma_f32_16x16x32_f16(pf[8 + i], w[24 + i], ac[i & 3], 0, 0, 0);
#pragma unroll
      for (int i = 0; i < 16; ++i)
        ac[i & 3] = __builtin_amdgcn_mfma_f32_16x16x32_f16(hh[i], w[8 + i], ac[i & 3], 0, 0, 0);
    }
    f32x4 acc = (ac[0] + ac[1]) + (ac[2] + ac[3]);
    // D[m][n]: m = (lane>>4)*4 + j (batch in tile), n = lane&15 (gate row)
#pragma unroll
    for (int j = 0; j < 4; ++j)
      s_scr[(wave << 4) + ((lane >> 4) << 2) + j][lane & 15] = acc[j];
    lds_barrier();                                   // #1 (lgkm-only)

    float4 ho = {0.f, 0.f, 0.f, 0.f};                // main out, stored post-arrive
    if (tid < 64) {
      // ---- epilogue (wave 0): one batch per thread, 4 units ----
      const int eb = tid;
      if (isDyn) {                                   // rare cd fixup (pv == t-1)
        const int cneed = s_rc[pb][eb];
        if (__any(cneed)) {
          if (cneed) cvp = scload16f(s_aC[pb][eb] + u0);
          __builtin_amdgcn_sched_barrier(0);
        }
      }
      float g[16];
#pragma unroll
      for (int n = 0; n < 16; ++n) g[n] = s_scr[eb][n] + s_bias[n];
      if (!isDyn) {
        union { f16 h[4]; unsigned long long u; } pk;
#pragma unroll
        for (int un = 0; un < 4; ++un) {
          float c = sigm(g[4 + un]) * creg[un] + sigm(g[un]) * tanh_fast(g[8 + un]);
          creg[un] = c;
          float h = sigm(g[12 + un]) * tanh_fast(c);
          (&ho.x)[un] = h;
          pk.h[un] = (f16)h;
        }
        // tiled h publish: 64 lanes x 8B = contiguous, fully-covered 512B
        cstore8(&p.Hhist[(size_t)(t + 1) * 32768 + (size_t)(u0 >> 2) * 256
                         + (size_t)eb * 4], pk.u);
      } else {
        const float cold[4] = {cvp.x, cvp.y, cvp.z, cvp.w};
        f32x4 co;
        union { f16 h[4]; unsigned long long u; } pk;
#pragma unroll
        for (int un = 0; un < 4; ++un) {
          float c = sigm(g[4 + un]) * cold[un] + sigm(g[un]) * tanh_fast(g[8 + un]);
          float h = sigm(g[12 + un]) * tanh_fast(c);
          pk.h[un] = (f16)h;
          co[un] = c;
        }
        if (s_dynw[pb][eb]) {
          cstore8(&p.HdHist[((size_t)t * B_ + eb) * D_ + u0], pk.u);
          cstore16(&p.CdHist[((size_t)t * B_ + eb) * D_ + u0], co);
        }
      }
    } else if (tid < 128 && t + 1 < T_) {
      // ---- wave 1: resolve next step's pointers concurrently ----
      resolve(p, isDyn, t + 1, tid - 64, t,
              s_aN[pb ^ 1], s_aX[pb ^ 1], s_aC[pb ^ 1], s_dynw[pb ^ 1], s_rc[pb ^ 1]);
    }
    lds_barrier();                                   // #2 (lgkm-only; no drain)

    if (t + 1 < T_) {
      // ---- wave0-private drain + arrive (out store NOT in the drain) ----
      if (wave == 0) {
        asm volatile("s_waitcnt vmcnt(0)" ::: "memory");
        if (tid == 0)
          __hip_atomic_fetch_add(&p.cnt[(blk & (NSH_ - 1)) << 4], 1u,
                                 __ATOMIC_RELAXED, __HIP_MEMORY_SCOPE_AGENT);
      }
      // ---- out store after the arrive (plain cached; acked by next drain) ----
      if (tid < 64 && !isDyn)
        *(float4*)&p.out[((size_t)tid * T_ + t) * H_ + u0] = ho;
      // ---- prefetch step-independent slices for t+1 (flies during poll) ----
      {
        const f16* pN2 = s_aN[pb ^ 1][b];
        const f16* pX2 = s_aX[pb ^ 1][b];
#pragma unroll
        for (int i = 0; i < 8; ++i) pf[i] = *(const f16x8*)(pN2 + i * 32 + ko);
#pragma unroll
        for (int i = 0; i < 8; ++i) pf[8 + i] = *(const f16x8*)(pX2 + i * 32 + ko);
        if (isDyn && tid < 64) cvp = *(const float4*)(s_aC[pb ^ 1][tid] + u0);
      }
      // ---- wave 1 polls (1 lane : 1 shard line) ----
      if (wave == 1) {
        const unsigned tgt = (unsigned)(t + 1) * PER_SHARD_;
        unsigned it = 0;
        while (__hip_atomic_load(&p.cnt[lane << 4], __ATOMIC_RELAXED,
                                 __HIP_MEMORY_SCOPE_AGENT) < tgt &&
               ++it < POLL_CAP_)
          __builtin_amdgcn_s_sleep(1);
      }
      lds_barrier();                                 // #3 release (lgkm-only)
    } else {
      // last step: just store out
      if (tid < 64 && !isDyn)
        *(float4*)&p.out[((size_t)tid * T_ + t) * H_ + u0] = ho;
    }
  }
}

extern "C" void kernel_launch(void* const* d_in, const int* in_sizes, int n_in,
                              void* d_out, int out_size, void* d_ws, size_t ws_size,
                              hipStream_t stream) {
  (void)in_sizes; (void)n_in; (void)out_size;
  const int* n_input   = (const int*)d_in[0];
  const int* t_input   = (const int*)d_in[1];
  const int* s2d       = (const int*)d_in[3];
  const float* embN    = (const float*)d_in[5];
  const float* embT    = (const float*)d_in[6];
  const float* W_ih    = (const float*)d_in[7];
  const float* W_hh    = (const float*)d_in[8];
  const float* b_ih    = (const float*)d_in[9];
  const float* b_hh    = (const float*)d_in[10];
  const float* Wd_ih   = (const float*)d_in[11];
  const float* Wd_hh   = (const float*)d_in[12];
  const float* bd_ih   = (const float*)d_in[13];
  const float* bd_hh   = (const float*)d_in[14];
  const float* hid_init  = (const float*)d_in[15];
  const float* cell_init = (const float*)d_in[16];
  const float* dyn_init_h = (const float*)d_in[17];
  const float* dyn_init_c = (const float*)d_in[18];

  char* ws = (char*)d_ws;
  unsigned* cnt  = (unsigned*)(ws + OFF_CNT);
  f16* embN16    = (f16*)(ws + OFF_EMBN);
  f16* embT16    = (f16*)(ws + OFF_EMBT);
  f16* dynih16   = (f16*)(ws + OFF_DINH);
  int* prev      = (int*)(ws + OFF_PREV);
  f16* Hhist     = (f16*)(ws + OFF_HH);
  f16* HdHist    = (f16*)(ws + OFF_HD);
  float* CdHist  = (float*)(ws + OFF_CD);
  if (ws_size < WS_NEED) return;

  setup_kernel<<<dim3((VN_ * EN_ + NTHR_ - 1) / NTHR_), dim3(NTHR_), 0, stream>>>(
      embN, embT, hid_init, dyn_init_h, embN16, embT16, dynih16, Hhist, cnt);
  prev_kernel<<<dim3((B_ * T_ + NTHR_ - 1) / NTHR_), dim3(NTHR_), 0, stream>>>(
      t_input, s2d, prev);

  RnnParams prm;
  prm.n_input = n_input; prm.t_input = t_input; prm.s2d = s2d;
  prm.W_ih = W_ih; prm.W_hh = W_hh; prm.b_ih = b_ih; prm.b_hh = b_hh;
  prm.Wd_ih = Wd_ih; prm.Wd_hh = Wd_hh; prm.bd_ih = bd_ih; prm.bd_hh = bd_hh;
  prm.cell_init = cell_init; prm.dyn_init_c = dyn_init_c;
  prm.embN16 = embN16; prm.embT16 = embT16; prm.dynih16 = dynih16;
  prm.prev = prev; prm.Hhist = Hhist; prm.HdHist = HdHist; prm.CdHist = CdHist;
  prm.out = (float*)d_out; prm.cnt = cnt;

  void* args[] = { &prm };
  hipError_t e = hipLaunchCooperativeKernel((const void*)rnn_main,
                                            dim3(NBLK_), dim3(NTHR_), args, 0, stream);
  if (e != hipSuccess) {
    rnn_main<<<dim3(NBLK_), dim3(NTHR_), 0, stream>>>(prm);
  }
}